// Round 14
// baseline (187.970 us; speedup 1.0000x reference)
//
#include <hip/hip_runtime.h>
#include <hip/hip_fp16.h>
#include <hip/hip_cooperative_groups.h>
#include <math.h>

namespace cg = cooperative_groups;

#define BB 512
#define SS 100
#define DE 150
#define DM 300   // 2*D_E (also == D_IN)
#define LL 101
#define NH 2

typedef _Float16 f16x8 __attribute__((ext_vector_type(8)));
typedef float f32x4 __attribute__((ext_vector_type(4)));

// ---- ws layout (float offsets) ----
#define WS_CLS    0        // [300]
#define WS_QK     320      // [2][300]
#define WS_CVEC   1200     // [300]
#define WS_COLSUM 1536     // [300]
#define WS_CST0   1856     // [2]
#define WS_STATS  1860     // [0]=a1 [1]=beta1
#define WS_G      2176     // [1200][2]
#define WS_P3     5248     // [15][2][300]
#define WS_PART1  14336    // [16][2]   (kV phase blocks)
#define WS_PART2  15360    // [256][2]  (k5 phase blocks)
#define WS_MSA    16384                     // [512][600] f32
#define WS_Y1     (WS_MSA + 512*600)        // [512][300]  ends 477184
#define WS_WPF    477184   // fp16 [40][160][8] = 102,400 B (25,600 f32)
#define WS_WVF    502784   // fp16 [2][40][320][8] = 409,600 B (102,400 f32)
#define WS_ZB16   605184   // fp16 [2][512][320] = 655,360 B (163,840 f32)
#define WS_Q0P    769024   // [10][2][300] q0 partials

// ---------------- kC1: q0p | Wp1 partials | cls | G | CST0 | Wpf | Wvf ----------------
__global__ void kC1(const float* __restrict__ pos, const float* __restrict__ cle,
                    const float* __restrict__ Wq, const float* __restrict__ Wp1,
                    const float* __restrict__ Wp, const float* __restrict__ Wv,
                    const float* __restrict__ f1W, const float* __restrict__ f2W,
                    const float* __restrict__ f1b, const float* __restrict__ f2b,
                    float* __restrict__ ws) {
  __shared__ float cls[DM];
  int b = blockIdx.x, tid = threadIdx.x;
  if (b < 35) {
    for (int i = tid; i < DM; i += 256) cls[i] = (i < DE) ? cle[i] : pos[i - DE];
    __syncthreads();
  }
  if (b < 20) {
    int p = b >> 1, h = b & 1;
    const float* wqh = Wq + h * DM * DM;
    int d0 = p * 30;
    for (int e = tid; e < DM; e += 256) {
      float acc = 0.f;
#pragma unroll
      for (int d = 0; d < 30; ++d) acc += cls[d0 + d] * wqh[(d0 + d) * DM + e];
      ws[WS_Q0P + p * 600 + h * 300 + e] = acc;
    }
  } else if (b < 35) {
    int kb = b - 20;
    for (int n = tid; n < DM; n += 256) {
      float cs = 0.f, cv = 0.f;
      for (int k = kb * 60; k < kb * 60 + 60; ++k) {
        float w = Wp1[k * 300 + n];
        if (k < 600) cs += w; else cv += cls[k - 600] * w;
      }
      ws[WS_P3 + kb * 600 + n] = cs;
      ws[WS_P3 + kb * 600 + 300 + n] = cv;
    }
  } else if (b == 35) {
    for (int i = tid; i < DM; i += 256)
      ws[WS_CLS + i] = (i < DE) ? cle[i] : pos[i - DE];
  } else if (b < 111) {
    int wave = tid >> 6, lane = tid & 63;
    int kbase = (b - 36) * 16 + wave * 4;
#pragma unroll
    for (int j = 0; j < 4; ++j) {
      int k = kbase + j;
      const float* r = f1W + k * 512;
      float a0 = 0.f, a1 = 0.f;
      for (int m = lane; m < 512; m += 64) {
        float a = r[m];
        float2 f2 = *(const float2*)&f2W[m * 2];
        a0 += a * f2.x; a1 += a * f2.y;
      }
      for (int o = 32; o; o >>= 1) { a0 += __shfl_xor(a0, o); a1 += __shfl_xor(a1, o); }
      if (!lane) { ws[WS_G + k * 2] = a0; ws[WS_G + k * 2 + 1] = a1; }
    }
  } else if (b == 111) {
    int wave = tid >> 6, lane = tid & 63;
    if (wave < 2) {
      float acc = 0.f;
      for (int m = lane; m < 512; m += 64) acc += f1b[m] * f2W[m * 2 + wave];
      for (int o = 32; o; o >>= 1) acc += __shfl_xor(acc, o);
      if (!lane) ws[WS_CST0 + wave] = f2b[wave] + acc;
    }
  } else if (b < 137) {
    int idx = (b - 112) * 256 + tid;       // < 6400
    int kq = idx / 160, n = idx % 160;
    f16x8 pk;
#pragma unroll
    for (int j = 0; j < 8; ++j) {
      int k = kq * 8 + j;
      float v = (k < DM && n < DE) ? Wp[k * DE + n] : 0.f;
      pk[j] = (_Float16)v;
    }
    *(f16x8*)((char*)ws + (size_t)WS_WPF * 4 + (size_t)idx * 16) = pk;
  } else {
    int idx = (b - 137) * 256 + tid;       // < 25600
    int h = idx / 12800, rem = idx % 12800;
    int kq = rem / 320, n = rem % 320;
    f16x8 pk;
#pragma unroll
    for (int j = 0; j < 8; ++j) {
      int k = kq * 8 + j;
      float v = (k < DM && n < DM) ? Wv[h * DM * DM + k * DM + n] : 0.f;
      pk[j] = (_Float16)v;
    }
    *(f16x8*)((char*)ws + (size_t)WS_WVF * 4 + (size_t)idx * 16) = pk;
  }
}

// ---------------- kC2p: qk (blocks 0-149) | combine colsum/cvec (block 150) ----------------
__global__ void kC2p(const float* __restrict__ Wk, const float* __restrict__ bp1,
                     float* __restrict__ ws) {
  int b = blockIdx.x, tid = threadIdx.x;
  if (b == 150) {
    for (int n = tid; n < DM; n += 256) {
      float cs = 0.f, cv = bp1[n];
      for (int p = 0; p < 15; ++p) {
        cs += ws[WS_P3 + p * 600 + n];
        cv += ws[WS_P3 + p * 600 + 300 + n];
      }
      ws[WS_COLSUM + n] = cs;
      ws[WS_CVEC + n] = cv;
    }
    return;
  }
  __shared__ float q0s[NH * DM];
  for (int i = tid; i < NH * DM; i += 256) {
    float s = 0.f;
#pragma unroll
    for (int p = 0; p < 10; ++p) s += ws[WS_Q0P + p * 600 + i];
    q0s[i] = s;
  }
  __syncthreads();
  int wave = tid >> 6, lane = tid & 63;
  int idx = b * 4 + wave;            // < 600
  int h = idx / DM, d = idx % DM;
  const float* w = Wk + h * DM * DM + d * DM;
  const float* q = q0s + h * DM;
  float acc = 0.f;
  for (int e = lane; e < DM; e += 64) acc += w[e] * q[e];
  for (int o = 32; o; o >>= 1) acc += __shfl_xor(acc, o);
  if (!lane) ws[WS_QK + idx] = acc;
}

// ---------------- kA: MFMA h-GEMM -> cpos/s0 -> scores -> softmax -> zbar16 ----------------
// aux layout: [0,600) qk full | [600,900) cls | [900,1102) scores | [1102,1304) p
__launch_bounds__(512, 4)
__global__ void kA(const float* __restrict__ x, const float* __restrict__ bp,
                   const float* __restrict__ pos, float* __restrict__ ws) {
  __shared__ __align__(16) char smem[41696];
  __half (*hb)[DE + 2] = (__half(*)[DE + 2])smem;
  _Float16* wpt0 = (_Float16*)(smem);
  _Float16* xs0  = (_Float16*)(smem + 10240);
  _Float16* wpt1 = (_Float16*)(smem + 18240);
  _Float16* xs1  = (_Float16*)(smem + 28480);
  float* aux = (float*)(smem + 36480);

  int b = blockIdx.x, tid = threadIdx.x;
  int w = tid >> 6, lane = tid & 63;
  int l16 = lane & 15, lg = lane >> 4;
  int wm = w >> 2, wn = w & 3;
  int nnt = (wn < 3) ? 3 : 1;
  int nt0 = (wn < 3) ? wn * 3 : 9;

  const float* xb = x + b * (SS * DM);
  const char* wpf = (const char*)ws + (size_t)WS_WPF * 4;
  int rowl[4];
#pragma unroll
  for (int mt = 0; mt < 4; ++mt) {
    int r = wm * 64 + mt * 16 + l16;
    rowl[mt] = (r < SS) ? r : (SS - 1);
  }

  f32x4 acc[4][3];
#pragma unroll
  for (int mt = 0; mt < 4; ++mt)
#pragma unroll
    for (int nti = 0; nti < 3; ++nti) acc[mt][nti] = (f32x4){0.f, 0.f, 0.f, 0.f};

  float xr[4][2];
  float4 wa, wb2;

#define XLOAD(S)                                                               \
  { int kc_ = (S) * 32;                                                        \
    _Pragma("unroll")                                                          \
    for (int i_ = 0; i_ < 4; ++i_) {                                           \
      int t_ = tid + 512 * i_;                                                 \
      if (t_ < 1600) {                                                         \
        int r_ = t_ >> 4, c_ = t_ & 15, k_ = kc_ + 2 * c_;                     \
        if (k_ + 1 < DM) {                                                     \
          float2 v_ = *(const float2*)(xb + r_ * DM + k_);                     \
          xr[i_][0] = v_.x; xr[i_][1] = v_.y;                                  \
        } else {                                                               \
          xr[i_][0] = (k_ < DM) ? xb[r_ * DM + k_] : 0.f;                      \
          xr[i_][1] = 0.f;                                                     \
        } } } }

#define XWRITE(XP)                                                             \
  { _Pragma("unroll")                                                          \
    for (int i_ = 0; i_ < 4; ++i_) {                                           \
      int t_ = tid + 512 * i_;                                                 \
      if (t_ < 1600) {                                                         \
        int r_ = t_ >> 4, c_ = t_ & 15;                                        \
        *(__half2*)((char*)(XP) + r_ * 80 + c_ * 4) =                          \
            __floats2half2_rn(xr[i_][0], xr[i_][1]);                           \
      } } }

#define WLOAD(S)                                                               \
  { const char* s_ = wpf + (size_t)(S) * 10240;                                \
    wa = *(const float4*)(s_ + tid * 16);                                      \
    if (tid < 128) wb2 = *(const float4*)(s_ + (tid + 512) * 16); }

#define WWRITE(WP)                                                             \
  { *(float4*)((char*)(WP) + tid * 16) = wa;                                   \
    if (tid < 128) *(float4*)((char*)(WP) + (tid + 512) * 16) = wb2; }

  XLOAD(0); WLOAD(0);
  XWRITE(xs0); WWRITE(wpt0);
  __syncthreads();

  for (int s = 0; s < 10; ++s) {
    _Float16* wc = (s & 1) ? wpt1 : wpt0;
    _Float16* xc = (s & 1) ? xs1 : xs0;
    _Float16* wnx = (s & 1) ? wpt0 : wpt1;
    _Float16* xnx = (s & 1) ? xs0 : xs1;
    if (s < 9) { WLOAD(s + 1); XLOAD(s + 1); }
    f16x8 Bf[3];
#pragma unroll
    for (int nti = 0; nti < 3; ++nti)
      if (nti < nnt)
        Bf[nti] = *(const f16x8*)(wc + ((lg * 160 + (nt0 + nti) * 16 + l16) * 8));
#pragma unroll
    for (int mt = 0; mt < 4; ++mt) {
      f16x8 Af = *(const f16x8*)(xc + rowl[mt] * 40 + lg * 8);
#pragma unroll
      for (int nti = 0; nti < 3; ++nti)
        if (nti < nnt)
          acc[mt][nti] = __builtin_amdgcn_mfma_f32_16x16x32_f16(Af, Bf[nti], acc[mt][nti], 0, 0, 0);
    }
    if (s < 9) { WWRITE(wnx); XWRITE(xnx); }
    __syncthreads();
  }

  // hb = relu(acc + bp) fp16 (aliases dead GEMM buffers)
#pragma unroll
  for (int nti = 0; nti < 3; ++nti) {
    if (nti < nnt) {
      int col = (nt0 + nti) * 16 + l16;
      float bpv = (col < DE) ? bp[col] : 0.f;
#pragma unroll
      for (int mt = 0; mt < 4; ++mt) {
        int rbase = wm * 64 + mt * 16 + lg * 4;
        f32x4 v = acc[mt][nti];
#pragma unroll
        for (int reg = 0; reg < 4; ++reg) {
          int row = rbase + reg;
          if (row < SS && col < DE) {
            float hv = v[reg] + bpv;
            hb[row][col] = __float2half(hv > 0.f ? hv : 0.f);
          }
        }
      }
    }
  }
  // aux: full qk + cls
  for (int i = tid; i < 600; i += 512) aux[i] = ws[WS_QK + i];
  for (int i = tid; i < DM; i += 512) aux[600 + i] = ws[WS_CLS + i];
  __syncthreads();

  // phase 2a: cpos (pair-per-output) + s0 -> score slots
  if (tid < 400) {
    int o = tid >> 1, half = tid & 1;
    int tt = o >> 1, hh = o & 1;
    const float* pr = pos + (tt + 1) * DE;
    const float* qk2 = &aux[hh * 300 + DE];
    float s = 0.f;
    for (int j = half; j < DE; j += 2) s += pr[j] * qk2[j];
    s += __shfl_xor(s, 1);
    if (!half) aux[900 + hh * LL + tt + 1] = s;
  } else if (tid == 400 || tid == 401) {
    int hh = tid - 400;
    float s = 0.f;
    for (int d = 0; d < DM; ++d) s += aux[600 + d] * aux[hh * 300 + d];
    aux[900 + hh * LL] = s;
  }
  __syncthreads();

  // phase 2b: scores += h . qk
  if (tid < NH * SS) {
    int hh = tid / SS, tt = tid % SS;
    const __half2* hr = (const __half2*)&hb[tt][0];
    const float* qr = &aux[hh * 300];
    float s = 0.f;
    for (int j2 = 0; j2 < DE / 2; ++j2) {
      float2 hv = __half22float2(hr[j2]);
      float2 qv = *(const float2*)&qr[2 * j2];
      s += hv.x * qv.x + hv.y * qv.y;
    }
    aux[900 + hh * LL + tt + 1] += s;
  }
  __syncthreads();

  // phase 3: softmax (one wave per head)
  if (w < NH) {
    float v0 = aux[900 + w * LL + lane];
    float v1 = (lane + 64 < LL) ? aux[900 + w * LL + lane + 64] : -1e30f;
    float m = fmaxf(v0, v1);
    for (int o = 32; o; o >>= 1) m = fmaxf(m, __shfl_xor(m, o));
    float e0 = expf(v0 - m);
    float e1 = (lane + 64 < LL) ? expf(v1 - m) : 0.f;
    float s = e0 + e1;
    for (int o = 32; o; o >>= 1) s += __shfl_xor(s, o);
    float inv = 1.f / s;
    aux[1102 + w * LL + lane] = e0 * inv;
    if (lane + 64 < LL) aux[1102 + w * LL + lane + 64] = e1 * inv;
  }
  __syncthreads();

  // phase 4: zbar -> global fp16 [h][512][320]
  __half* zb16 = (__half*)((char*)ws + (size_t)WS_ZB16 * 4);
  for (int o = tid; o < NH * DM; o += 512) {
    int hh = o / DM, d = o % DM;
    const float* p = &aux[1102 + hh * LL];
    float acc2 = p[0] * aux[600 + d];
    if (d < DE) {
      for (int t = 1; t <= SS; ++t) acc2 += p[t] * __half2float(hb[t - 1][d]);
    } else {
      int dd = d - DE;
      for (int t = 1; t <= SS; ++t) acc2 += p[t] * pos[t * DE + dd];
    }
    zb16[((size_t)hh * 512 + b) * 320 + d] = __float2half(acc2);
  }
  if (tid < 40) {
    int hh = tid / 20, dd = 300 + tid % 20;
    zb16[((size_t)hh * 512 + b) * 320 + dd] = __float2half(0.f);
  }
}

// ---------------- kTail (cooperative): phase V -> sync -> phase 5 -> sync -> phase 7 ----
__launch_bounds__(512)
__global__ void kTail(const float* __restrict__ Wp1, const float* __restrict__ g1,
                      const float* __restrict__ b1, const float* __restrict__ g2,
                      const float* __restrict__ b2, float* __restrict__ out,
                      float* __restrict__ ws) {
  cg::grid_group grid = cg::this_grid();
  __shared__ __align__(16) float sm[2424];
  int blk = blockIdx.x, tid = threadIdx.x;
  int w = tid >> 6, lane = tid & 63;

  // ======== phase V: msa = zbar16 @ Wvf (blocks 0-15) ========
  if (blk < 16) {
    int mtile = blk >> 2, nb = (blk >> 1) & 1, h = blk & 1;
    int l16 = lane & 15, lg = lane >> 4;
    int wm = w >> 2, wn = w & 3;
    int nnt = (wn < 3) ? 3 : 1;
    int nt0 = (wn < 3) ? wn * 3 : 9;
    int mbase = mtile * 128;
    const __half* zb16 = (const __half*)((const char*)ws + (size_t)WS_ZB16 * 4) + (size_t)h * 512 * 320;
    const __half* wvf  = (const __half*)((const char*)ws + (size_t)WS_WVF * 4) + (size_t)h * 40 * 320 * 8;
    int brow[4];
#pragma unroll
    for (int mt = 0; mt < 4; ++mt) brow[mt] = mbase + wm * 64 + mt * 16 + l16;
    f32x4 acc[4][3];
#pragma unroll
    for (int mt = 0; mt < 4; ++mt)
#pragma unroll
      for (int nti = 0; nti < 3; ++nti) acc[mt][nti] = (f32x4){0.f, 0.f, 0.f, 0.f};
    for (int s = 0; s < 10; ++s) {
      f16x8 Bf[3];
#pragma unroll
      for (int nti = 0; nti < 3; ++nti)
        if (nti < nnt) {
          int n = nb * 160 + (nt0 + nti) * 16 + l16;
          Bf[nti] = *(const f16x8*)&wvf[((size_t)(s * 4 + lg) * 320 + n) * 8];
        }
#pragma unroll
      for (int mt = 0; mt < 4; ++mt) {
        f16x8 Af = *(const f16x8*)&zb16[(size_t)brow[mt] * 320 + s * 32 + lg * 8];
#pragma unroll
        for (int nti = 0; nti < 3; ++nti)
          if (nti < nnt)
            acc[mt][nti] = __builtin_amdgcn_mfma_f32_16x16x32_f16(Af, Bf[nti], acc[mt][nti], 0, 0, 0);
      }
    }
    float s_ = 0.f, ss_ = 0.f;
#pragma unroll
    for (int nti = 0; nti < 3; ++nti) {
      if (nti < nnt) {
        int col = nb * 160 + (nt0 + nti) * 16 + l16;
        if (col < DM) {
#pragma unroll
          for (int mt = 0; mt < 4; ++mt) {
            int rbase = mbase + wm * 64 + mt * 16 + lg * 4;
            f32x4 v = acc[mt][nti];
#pragma unroll
            for (int reg = 0; reg < 4; ++reg) {
              float val = v[reg];
              ws[WS_MSA + (rbase + reg) * 600 + h * DM + col] = val;
              s_ += val; ss_ += val * val;
            }
          }
        }
      }
    }
    for (int o = 32; o; o >>= 1) { s_ += __shfl_xor(s_, o); ss_ += __shfl_xor(ss_, o); }
    if (!lane) { sm[2400 + w] = s_; sm[2408 + w] = ss_; }
    __syncthreads();
    if (!tid) {
      float S = 0.f, SS2 = 0.f;
      for (int i = 0; i < 8; ++i) { S += sm[2400 + i]; SS2 += sm[2408 + i]; }
      ws[WS_PART1 + blk * 2] = S;
      ws[WS_PART1 + blk * 2 + 1] = SS2;
    }
  }
  grid.sync();

  // ======== phase 5: bn1 finalize + y1 (all 256 blocks, 2 batches each) ========
  {
    float* ab   = sm;          // [2][600]
    float* part = sm + 1200;   // [2][2][300]
    float* shr  = sm + 2400;   // [2][8]
    float* s_ab = sm + 2416;   // [2]
    int b0 = blk * 2;
    for (int i = tid; i < 1200; i += 512) ab[i] = ws[WS_MSA + b0 * 600 + i];
    {
      float s = 0.f, ss = 0.f;
      if (tid < 16) { s = ws[WS_PART1 + tid * 2]; ss = ws[WS_PART1 + tid * 2 + 1]; }
      for (int o = 32; o; o >>= 1) { s += __shfl_xor(s, o); ss += __shfl_xor(ss, o); }
      if (!lane) { shr[w] = s; shr[8 + w] = ss; }
    }
    __syncthreads();
    if (!tid) {
      float S = 0.f, SS2 = 0.f;
      for (int i = 0; i < 8; ++i) { S += shr[i]; SS2 += shr[8 + i]; }
      float n = (float)(BB * 600);
      float mean = S / n, var = SS2 / n - mean * mean;
      float a = (1.f / sqrtf(var + 1e-5f)) * g1[0];
      s_ab[0] = a; s_ab[1] = b1[0] - a * mean;
      if (blk == 0) { ws[WS_STATS + 0] = a; ws[WS_STATS + 1] = s_ab[1]; }
    }
    __syncthreads();
    int g = tid >> 8, t = tid & 255;
    int kbeg = g * 300, kend = kbeg + 300;
    for (int n = t; n < 300; n += 256) {
      float a0 = 0.f, a1v = 0.f;
      for (int k = kbeg; k < kend; ++k) {
        float wq = Wp1[k * 300 + n];
        a0 += ab[k] * wq;
        a1v += ab[600 + k] * wq;
      }
      part[g * 600 + n] = a0;
      part[g * 600 + 300 + n] = a1v;
    }
    __syncthreads();
    float a1 = s_ab[0], beta1 = s_ab[1];
    float s2 = 0.f, ss2 = 0.f;
    for (int n = tid; n < 300; n += 512) {
      float c = beta1 * ws[WS_COLSUM + n] + ws[WS_CVEC + n];
      float v0 = a1 * (part[n] + part[600 + n]) + c;
      float v1 = a1 * (part[300 + n] + part[900 + n]) + c;
      v0 = v0 > 0.f ? v0 : 0.f;
      v1 = v1 > 0.f ? v1 : 0.f;
      ws[WS_Y1 + b0 * 300 + n] = v0;
      ws[WS_Y1 + (b0 + 1) * 300 + n] = v1;
      s2 += v0 + v1; ss2 += v0 * v0 + v1 * v1;
    }
    for (int o = 32; o; o >>= 1) { s2 += __shfl_xor(s2, o); ss2 += __shfl_xor(ss2, o); }
    if (!lane) { shr[w] = s2; shr[8 + w] = ss2; }
    __syncthreads();
    if (!tid) {
      float S = 0.f, SS2 = 0.f;
      for (int i = 0; i < 8; ++i) { S += shr[i]; SS2 += shr[8 + i]; }
      ws[WS_PART2 + blk * 2] = S;
      ws[WS_PART2 + blk * 2 + 1] = SS2;
    }
  }
  grid.sync();

  // ======== phase 7: bn2 finalize + consts + out (blocks 0-63, 8 batches each) ========
  if (blk < 64) {
    float* Gs  = sm;           // [2400]
    float* shr = sm + 2400;    // [2][8]
    float* cc  = sm + 2416;    // [4]
    for (int i = tid; i < 2400; i += 512) Gs[i] = ws[WS_G + i];
    {
      float s = 0.f, ss = 0.f;
      if (tid < 256) { s = ws[WS_PART2 + tid * 2]; ss = ws[WS_PART2 + tid * 2 + 1]; }
      for (int o = 32; o; o >>= 1) { s += __shfl_xor(s, o); ss += __shfl_xor(ss, o); }
      if (!lane) { shr[w] = s; shr[8 + w] = ss; }
    }
    __syncthreads();
    if (!tid) {
      float S = 0.f, SS2 = 0.f;
      for (int i = 0; i < 8; ++i) { S += shr[i]; SS2 += shr[8 + i]; }
      float n = (float)(BB * 300);
      float mean = S / n, var = SS2 / n - mean * mean;
      float a = (1.f / sqrtf(var + 1e-5f)) * g2[0];
      cc[0] = a; cc[1] = b2[0] - a * mean;
    }
    __syncthreads();
    if (tid < 2) {
      int c = tid;
      float sg1 = 0.f, sg2 = 0.f, sg3 = 0.f;
      for (int k = 0; k < 300; ++k) sg1 += Gs[k * 2 + c];
      for (int k = 300; k < 900; ++k) sg2 += Gs[k * 2 + c];
      for (int j = 0; j < 300; ++j) sg3 += ws[WS_CLS + j] * Gs[(900 + j) * 2 + c];
      cc[2 + c] = ws[WS_CST0 + c] + sg3 + cc[1] * sg1 + ws[WS_STATS + 1] * sg2;
    }
    __syncthreads();
    int b = blk * 8 + w;
    float a1 = ws[WS_STATS + 0], a2 = cc[0];
    const float* y1 = ws + WS_Y1 + b * 300;
    const float* ms = ws + WS_MSA + b * 600;
    float o0 = 0.f, o1 = 0.f, p0 = 0.f, p1 = 0.f;
    for (int k = lane; k < 300; k += 64) { float v = y1[k]; o0 += v * Gs[k * 2]; o1 += v * Gs[k * 2 + 1]; }
    for (int j = lane; j < 600; j += 64) { float v = ms[j]; p0 += v * Gs[(300 + j) * 2]; p1 += v * Gs[(300 + j) * 2 + 1]; }
    for (int o = 32; o; o >>= 1) {
      o0 += __shfl_xor(o0, o); o1 += __shfl_xor(o1, o);
      p0 += __shfl_xor(p0, o); p1 += __shfl_xor(p1, o);
    }
    if (!lane) {
      out[b * 2] = a2 * o0 + a1 * p0 + cc[2];
      out[b * 2 + 1] = a2 * o1 + a1 * p1 + cc[3];
    }
  }
}

extern "C" void kernel_launch(void* const* d_in, const int* in_sizes, int n_in,
                              void* d_out, int out_size, void* d_ws, size_t ws_size,
                              hipStream_t stream) {
  const float* x    = (const float*)d_in[0];
  const float* Wp   = (const float*)d_in[1];
  const float* bp   = (const float*)d_in[2];
  const float* pos  = (const float*)d_in[3];
  const float* cle  = (const float*)d_in[4];
  const float* Wq   = (const float*)d_in[5];
  const float* Wk   = (const float*)d_in[6];
  const float* Wv   = (const float*)d_in[7];
  const float* bn1g = (const float*)d_in[8];
  const float* bn1b = (const float*)d_in[9];
  const float* Wp1  = (const float*)d_in[10];
  const float* bp1  = (const float*)d_in[11];
  const float* bn2g = (const float*)d_in[12];
  const float* bn2b = (const float*)d_in[13];
  const float* f1W  = (const float*)d_in[14];
  const float* f1b  = (const float*)d_in[15];
  const float* f2W  = (const float*)d_in[16];
  const float* f2b  = (const float*)d_in[17];
  float* ws = (float*)d_ws;
  float* out = (float*)d_out;

  hipLaunchKernelGGL(kC1, dim3(237), dim3(256), 0, stream, pos, cle, Wq, Wp1, Wp, Wv, f1W, f2W, f1b, f2b, ws);
  hipLaunchKernelGGL(kC2p, dim3(151), dim3(256), 0, stream, Wk, bp1, ws);
  hipLaunchKernelGGL(kA, dim3(512), dim3(512), 0, stream, x, bp, pos, ws);
  void* kt_args[] = {(void*)&Wp1, (void*)&bn1g, (void*)&bn1b, (void*)&bn2g,
                     (void*)&bn2b, (void*)&out, (void*)&ws};
  hipLaunchCooperativeKernel((void*)kTail, dim3(256), dim3(512), kt_args, 0, stream);
}

// Round 15
// 133.387 us; speedup vs baseline: 1.4092x; 1.4092x over previous
//
#include <hip/hip_runtime.h>
#include <hip/hip_fp16.h>
#include <math.h>

#define BB 512
#define SS 100
#define DE 150
#define DM 300   // 2*D_E (also == D_IN)
#define LL 101
#define NH 2

typedef _Float16 f16x8 __attribute__((ext_vector_type(8)));
typedef float f32x4 __attribute__((ext_vector_type(4)));

// ---- ws layout (float offsets) ----
#define WS_CLS    0        // [300]
#define WS_QK     320      // [2][300]
#define WS_CVEC   1200     // [300]
#define WS_COLSUM 1536     // [300]
#define WS_CST0   1856     // [2]
#define WS_STATS  1860     // [0]=a1 [1]=beta1
#define WS_G      2176     // [1200][2]
#define WS_P3     5248     // [15][2][300]
#define WS_PART1  14336    // [16][2]   (kV blocks)
#define WS_PART2  15360    // [256][2]  (k5 blocks)
#define WS_MSA    16384                     // [512][600] f32
#define WS_Y1     (WS_MSA + 512*600)        // [512][300]  ends 477184
#define WS_WPF    477184   // fp16 [40][160][8] = 102,400 B (25,600 f32)
#define WS_WVF    502784   // fp16 [2][40][320][8] = 409,600 B (102,400 f32)
#define WS_ZB16   605184   // fp16 [2][512][320] = 655,360 B (163,840 f32)
#define WS_Q0P    769024   // [10][2][300] q0 partials

// ---------------- kC1: q0p | Wp1 partials | cls | G | CST0 | Wpf | Wvf ----------------
__global__ void kC1(const float* __restrict__ pos, const float* __restrict__ cle,
                    const float* __restrict__ Wq, const float* __restrict__ Wp1,
                    const float* __restrict__ Wp, const float* __restrict__ Wv,
                    const float* __restrict__ f1W, const float* __restrict__ f2W,
                    const float* __restrict__ f1b, const float* __restrict__ f2b,
                    float* __restrict__ ws) {
  __shared__ float cls[DM];
  int b = blockIdx.x, tid = threadIdx.x;
  if (b < 35) {
    for (int i = tid; i < DM; i += 256) cls[i] = (i < DE) ? cle[i] : pos[i - DE];
    __syncthreads();
  }
  if (b < 20) {
    int p = b >> 1, h = b & 1;
    const float* wqh = Wq + h * DM * DM;
    int d0 = p * 30;
    for (int e = tid; e < DM; e += 256) {
      float acc = 0.f;
#pragma unroll
      for (int d = 0; d < 30; ++d) acc += cls[d0 + d] * wqh[(d0 + d) * DM + e];
      ws[WS_Q0P + p * 600 + h * 300 + e] = acc;
    }
  } else if (b < 35) {
    int kb = b - 20;
    for (int n = tid; n < DM; n += 256) {
      float cs = 0.f, cv = 0.f;
      for (int k = kb * 60; k < kb * 60 + 60; ++k) {
        float w = Wp1[k * 300 + n];
        if (k < 600) cs += w; else cv += cls[k - 600] * w;
      }
      ws[WS_P3 + kb * 600 + n] = cs;
      ws[WS_P3 + kb * 600 + 300 + n] = cv;
    }
  } else if (b == 35) {
    for (int i = tid; i < DM; i += 256)
      ws[WS_CLS + i] = (i < DE) ? cle[i] : pos[i - DE];
  } else if (b < 111) {
    int wave = tid >> 6, lane = tid & 63;
    int kbase = (b - 36) * 16 + wave * 4;
#pragma unroll
    for (int j = 0; j < 4; ++j) {
      int k = kbase + j;
      const float* r = f1W + k * 512;
      float a0 = 0.f, a1 = 0.f;
      for (int m = lane; m < 512; m += 64) {
        float a = r[m];
        float2 f2 = *(const float2*)&f2W[m * 2];
        a0 += a * f2.x; a1 += a * f2.y;
      }
      for (int o = 32; o; o >>= 1) { a0 += __shfl_xor(a0, o); a1 += __shfl_xor(a1, o); }
      if (!lane) { ws[WS_G + k * 2] = a0; ws[WS_G + k * 2 + 1] = a1; }
    }
  } else if (b == 111) {
    int wave = tid >> 6, lane = tid & 63;
    if (wave < 2) {
      float acc = 0.f;
      for (int m = lane; m < 512; m += 64) acc += f1b[m] * f2W[m * 2 + wave];
      for (int o = 32; o; o >>= 1) acc += __shfl_xor(acc, o);
      if (!lane) ws[WS_CST0 + wave] = f2b[wave] + acc;
    }
  } else if (b < 137) {
    int idx = (b - 112) * 256 + tid;       // < 6400
    int kq = idx / 160, n = idx % 160;
    f16x8 pk;
#pragma unroll
    for (int j = 0; j < 8; ++j) {
      int k = kq * 8 + j;
      float v = (k < DM && n < DE) ? Wp[k * DE + n] : 0.f;
      pk[j] = (_Float16)v;
    }
    *(f16x8*)((char*)ws + (size_t)WS_WPF * 4 + (size_t)idx * 16) = pk;
  } else {
    int idx = (b - 137) * 256 + tid;       // < 25600
    int h = idx / 12800, rem = idx % 12800;
    int kq = rem / 320, n = rem % 320;
    f16x8 pk;
#pragma unroll
    for (int j = 0; j < 8; ++j) {
      int k = kq * 8 + j;
      float v = (k < DM && n < DM) ? Wv[h * DM * DM + k * DM + n] : 0.f;
      pk[j] = (_Float16)v;
    }
    *(f16x8*)((char*)ws + (size_t)WS_WVF * 4 + (size_t)idx * 16) = pk;
  }
}

// ---------------- kC2p: qk (blocks 0-149) | combine colsum/cvec (block 150) ----------------
__global__ void kC2p(const float* __restrict__ Wk, const float* __restrict__ bp1,
                     float* __restrict__ ws) {
  int b = blockIdx.x, tid = threadIdx.x;
  if (b == 150) {
    for (int n = tid; n < DM; n += 256) {
      float cs = 0.f, cv = bp1[n];
      for (int p = 0; p < 15; ++p) {
        cs += ws[WS_P3 + p * 600 + n];
        cv += ws[WS_P3 + p * 600 + 300 + n];
      }
      ws[WS_COLSUM + n] = cs;
      ws[WS_CVEC + n] = cv;
    }
    return;
  }
  __shared__ float q0s[NH * DM];
  for (int i = tid; i < NH * DM; i += 256) {
    float s = 0.f;
#pragma unroll
    for (int p = 0; p < 10; ++p) s += ws[WS_Q0P + p * 600 + i];
    q0s[i] = s;
  }
  __syncthreads();
  int wave = tid >> 6, lane = tid & 63;
  int idx = b * 4 + wave;            // < 600
  int h = idx / DM, d = idx % DM;
  const float* w = Wk + h * DM * DM + d * DM;
  const float* q = q0s + h * DM;
  float acc = 0.f;
  for (int e = lane; e < DM; e += 64) acc += w[e] * q[e];
  for (int o = 32; o; o >>= 1) acc += __shfl_xor(acc, o);
  if (!lane) ws[WS_QK + idx] = acc;
}

// ---------------- kA: MFMA h-GEMM -> cpos/s0 -> scores -> softmax -> zbar16 ----------------
// aux layout: [0,600) qk full | [600,900) cls | [900,1102) scores | [1102,1304) p
__launch_bounds__(512, 4)
__global__ void kA(const float* __restrict__ x, const float* __restrict__ bp,
                   const float* __restrict__ pos, float* __restrict__ ws) {
  __shared__ __align__(16) char smem[41696];
  __half (*hb)[DE + 2] = (__half(*)[DE + 2])smem;
  _Float16* wpt0 = (_Float16*)(smem);
  _Float16* xs0  = (_Float16*)(smem + 10240);
  _Float16* wpt1 = (_Float16*)(smem + 18240);
  _Float16* xs1  = (_Float16*)(smem + 28480);
  float* aux = (float*)(smem + 36480);

  int b = blockIdx.x, tid = threadIdx.x;
  int w = tid >> 6, lane = tid & 63;
  int l16 = lane & 15, lg = lane >> 4;
  int wm = w >> 2, wn = w & 3;
  int nnt = (wn < 3) ? 3 : 1;
  int nt0 = (wn < 3) ? wn * 3 : 9;

  const float* xb = x + b * (SS * DM);
  const char* wpf = (const char*)ws + (size_t)WS_WPF * 4;
  int rowl[4];
#pragma unroll
  for (int mt = 0; mt < 4; ++mt) {
    int r = wm * 64 + mt * 16 + l16;
    rowl[mt] = (r < SS) ? r : (SS - 1);
  }

  f32x4 acc[4][3];
#pragma unroll
  for (int mt = 0; mt < 4; ++mt)
#pragma unroll
    for (int nti = 0; nti < 3; ++nti) acc[mt][nti] = (f32x4){0.f, 0.f, 0.f, 0.f};

  float xr[4][2];
  float4 wa, wb2;

#define XLOAD(S)                                                               \
  { int kc_ = (S) * 32;                                                        \
    _Pragma("unroll")                                                          \
    for (int i_ = 0; i_ < 4; ++i_) {                                           \
      int t_ = tid + 512 * i_;                                                 \
      if (t_ < 1600) {                                                         \
        int r_ = t_ >> 4, c_ = t_ & 15, k_ = kc_ + 2 * c_;                     \
        if (k_ + 1 < DM) {                                                     \
          float2 v_ = *(const float2*)(xb + r_ * DM + k_);                     \
          xr[i_][0] = v_.x; xr[i_][1] = v_.y;                                  \
        } else {                                                               \
          xr[i_][0] = (k_ < DM) ? xb[r_ * DM + k_] : 0.f;                      \
          xr[i_][1] = 0.f;                                                     \
        } } } }

#define XWRITE(XP)                                                             \
  { _Pragma("unroll")                                                          \
    for (int i_ = 0; i_ < 4; ++i_) {                                           \
      int t_ = tid + 512 * i_;                                                 \
      if (t_ < 1600) {                                                         \
        int r_ = t_ >> 4, c_ = t_ & 15;                                        \
        *(__half2*)((char*)(XP) + r_ * 80 + c_ * 4) =                          \
            __floats2half2_rn(xr[i_][0], xr[i_][1]);                           \
      } } }

#define WLOAD(S)                                                               \
  { const char* s_ = wpf + (size_t)(S) * 10240;                                \
    wa = *(const float4*)(s_ + tid * 16);                                      \
    if (tid < 128) wb2 = *(const float4*)(s_ + (tid + 512) * 16); }

#define WWRITE(WP)                                                             \
  { *(float4*)((char*)(WP) + tid * 16) = wa;                                   \
    if (tid < 128) *(float4*)((char*)(WP) + (tid + 512) * 16) = wb2; }

  XLOAD(0); WLOAD(0);
  XWRITE(xs0); WWRITE(wpt0);
  __syncthreads();

  for (int s = 0; s < 10; ++s) {
    _Float16* wc = (s & 1) ? wpt1 : wpt0;
    _Float16* xc = (s & 1) ? xs1 : xs0;
    _Float16* wnx = (s & 1) ? wpt0 : wpt1;
    _Float16* xnx = (s & 1) ? xs0 : xs1;
    if (s < 9) { WLOAD(s + 1); XLOAD(s + 1); }
    f16x8 Bf[3];
#pragma unroll
    for (int nti = 0; nti < 3; ++nti)
      if (nti < nnt)
        Bf[nti] = *(const f16x8*)(wc + ((lg * 160 + (nt0 + nti) * 16 + l16) * 8));
#pragma unroll
    for (int mt = 0; mt < 4; ++mt) {
      f16x8 Af = *(const f16x8*)(xc + rowl[mt] * 40 + lg * 8);
#pragma unroll
      for (int nti = 0; nti < 3; ++nti)
        if (nti < nnt)
          acc[mt][nti] = __builtin_amdgcn_mfma_f32_16x16x32_f16(Af, Bf[nti], acc[mt][nti], 0, 0, 0);
    }
    if (s < 9) { WWRITE(wnx); XWRITE(xnx); }
    __syncthreads();
  }

  // hb = relu(acc + bp) fp16 (aliases dead GEMM buffers)
#pragma unroll
  for (int nti = 0; nti < 3; ++nti) {
    if (nti < nnt) {
      int col = (nt0 + nti) * 16 + l16;
      float bpv = (col < DE) ? bp[col] : 0.f;
#pragma unroll
      for (int mt = 0; mt < 4; ++mt) {
        int rbase = wm * 64 + mt * 16 + lg * 4;
        f32x4 v = acc[mt][nti];
#pragma unroll
        for (int reg = 0; reg < 4; ++reg) {
          int row = rbase + reg;
          if (row < SS && col < DE) {
            float hv = v[reg] + bpv;
            hb[row][col] = __float2half(hv > 0.f ? hv : 0.f);
          }
        }
      }
    }
  }
  // aux: full qk + cls
  for (int i = tid; i < 600; i += 512) aux[i] = ws[WS_QK + i];
  for (int i = tid; i < DM; i += 512) aux[600 + i] = ws[WS_CLS + i];
  __syncthreads();

  // phase 2a: cpos (pair-per-output) + s0 -> score slots
  if (tid < 400) {
    int o = tid >> 1, half = tid & 1;
    int tt = o >> 1, hh = o & 1;
    const float* pr = pos + (tt + 1) * DE;
    const float* qk2 = &aux[hh * 300 + DE];
    float s = 0.f;
    for (int j = half; j < DE; j += 2) s += pr[j] * qk2[j];
    s += __shfl_xor(s, 1);
    if (!half) aux[900 + hh * LL + tt + 1] = s;
  } else if (tid == 400 || tid == 401) {
    int hh = tid - 400;
    float s = 0.f;
    for (int d = 0; d < DM; ++d) s += aux[600 + d] * aux[hh * 300 + d];
    aux[900 + hh * LL] = s;
  }
  __syncthreads();

  // phase 2b: scores += h . qk
  if (tid < NH * SS) {
    int hh = tid / SS, tt = tid % SS;
    const __half2* hr = (const __half2*)&hb[tt][0];
    const float* qr = &aux[hh * 300];
    float s = 0.f;
    for (int j2 = 0; j2 < DE / 2; ++j2) {
      float2 hv = __half22float2(hr[j2]);
      float2 qv = *(const float2*)&qr[2 * j2];
      s += hv.x * qv.x + hv.y * qv.y;
    }
    aux[900 + hh * LL + tt + 1] += s;
  }
  __syncthreads();

  // phase 3: softmax (one wave per head)
  if (w < NH) {
    float v0 = aux[900 + w * LL + lane];
    float v1 = (lane + 64 < LL) ? aux[900 + w * LL + lane + 64] : -1e30f;
    float m = fmaxf(v0, v1);
    for (int o = 32; o; o >>= 1) m = fmaxf(m, __shfl_xor(m, o));
    float e0 = expf(v0 - m);
    float e1 = (lane + 64 < LL) ? expf(v1 - m) : 0.f;
    float s = e0 + e1;
    for (int o = 32; o; o >>= 1) s += __shfl_xor(s, o);
    float inv = 1.f / s;
    aux[1102 + w * LL + lane] = e0 * inv;
    if (lane + 64 < LL) aux[1102 + w * LL + lane + 64] = e1 * inv;
  }
  __syncthreads();

  // phase 4: zbar -> global fp16 [h][512][320]
  __half* zb16 = (__half*)((char*)ws + (size_t)WS_ZB16 * 4);
  for (int o = tid; o < NH * DM; o += 512) {
    int hh = o / DM, d = o % DM;
    const float* p = &aux[1102 + hh * LL];
    float acc2 = p[0] * aux[600 + d];
    if (d < DE) {
      for (int t = 1; t <= SS; ++t) acc2 += p[t] * __half2float(hb[t - 1][d]);
    } else {
      int dd = d - DE;
      for (int t = 1; t <= SS; ++t) acc2 += p[t] * pos[t * DE + dd];
    }
    zb16[((size_t)hh * 512 + b) * 320 + d] = __float2half(acc2);
  }
  if (tid < 40) {
    int hh = tid / 20, dd = 300 + tid % 20;
    zb16[((size_t)hh * 512 + b) * 320 + dd] = __float2half(0.f);
  }
}

// ---------------- kV: msa = zbar16 @ Wvf (MFMA, L2-direct) + bn1 partials ----------------
__launch_bounds__(512, 4)
__global__ void kV(float* __restrict__ ws) {
  __shared__ float shp[2][8];
  int blk = blockIdx.x;
  int mtile = blk >> 2, nb = (blk >> 1) & 1, h = blk & 1;
  int tid = threadIdx.x;
  int w = tid >> 6, lane = tid & 63;
  int l16 = lane & 15, lg = lane >> 4;
  int wm = w >> 2, wn = w & 3;
  int nnt = (wn < 3) ? 3 : 1;
  int nt0 = (wn < 3) ? wn * 3 : 9;
  int mbase = mtile * 128;

  const __half* zb16 = (const __half*)((const char*)ws + (size_t)WS_ZB16 * 4) + (size_t)h * 512 * 320;
  const __half* wvf  = (const __half*)((const char*)ws + (size_t)WS_WVF * 4) + (size_t)h * 40 * 320 * 8;

  int brow[4];
#pragma unroll
  for (int mt = 0; mt < 4; ++mt) brow[mt] = mbase + wm * 64 + mt * 16 + l16;

  f32x4 acc[4][3];
#pragma unroll
  for (int mt = 0; mt < 4; ++mt)
#pragma unroll
    for (int nti = 0; nti < 3; ++nti) acc[mt][nti] = (f32x4){0.f, 0.f, 0.f, 0.f};

  for (int s = 0; s < 10; ++s) {
    f16x8 Bf[3];
#pragma unroll
    for (int nti = 0; nti < 3; ++nti)
      if (nti < nnt) {
        int n = nb * 160 + (nt0 + nti) * 16 + l16;
        Bf[nti] = *(const f16x8*)&wvf[((size_t)(s * 4 + lg) * 320 + n) * 8];
      }
#pragma unroll
    for (int mt = 0; mt < 4; ++mt) {
      f16x8 Af = *(const f16x8*)&zb16[(size_t)brow[mt] * 320 + s * 32 + lg * 8];
#pragma unroll
      for (int nti = 0; nti < 3; ++nti)
        if (nti < nnt)
          acc[mt][nti] = __builtin_amdgcn_mfma_f32_16x16x32_f16(Af, Bf[nti], acc[mt][nti], 0, 0, 0);
    }
  }

  float s_ = 0.f, ss_ = 0.f;
#pragma unroll
  for (int nti = 0; nti < 3; ++nti) {
    if (nti < nnt) {
      int col = nb * 160 + (nt0 + nti) * 16 + l16;
      if (col < DM) {
#pragma unroll
        for (int mt = 0; mt < 4; ++mt) {
          int rbase = mbase + wm * 64 + mt * 16 + lg * 4;
          f32x4 v = acc[mt][nti];
#pragma unroll
          for (int reg = 0; reg < 4; ++reg) {
            int row = rbase + reg;
            float val = v[reg];
            ws[WS_MSA + row * 600 + h * DM + col] = val;
            s_ += val; ss_ += val * val;
          }
        }
      }
    }
  }
  for (int o = 32; o; o >>= 1) { s_ += __shfl_xor(s_, o); ss_ += __shfl_xor(ss_, o); }
  if (!lane) { shp[0][w] = s_; shp[1][w] = ss_; }
  __syncthreads();
  if (!tid) {
    float S = 0.f, SS2 = 0.f;
    for (int i = 0; i < 8; ++i) { S += shp[0][i]; SS2 += shp[1][i]; }
    ws[WS_PART1 + blk * 2] = S;
    ws[WS_PART1 + blk * 2 + 1] = SS2;
  }
}

// ---------------- k5: bn1 finalize + y1 (split-K x2) + bn2 per-block partial ----------------
__launch_bounds__(512)
__global__ void k5(const float* __restrict__ Wp1, const float* __restrict__ g1,
                   const float* __restrict__ b1, float* __restrict__ ws) {
  __shared__ float ab[2][600];
  __shared__ float part[2][2][300];
  __shared__ float sh[2][8];
  __shared__ float s_a1, s_b1;
  int b0 = blockIdx.x * 2, tid = threadIdx.x;
  int wv = tid >> 6, ln = tid & 63;
  for (int i = tid; i < 1200; i += 512) ab[i / 600][i % 600] = ws[WS_MSA + b0 * 600 + i];
  {
    float s = 0.f, ss = 0.f;
    if (tid < 16) { s = ws[WS_PART1 + tid * 2]; ss = ws[WS_PART1 + tid * 2 + 1]; }
    for (int o = 32; o; o >>= 1) { s += __shfl_xor(s, o); ss += __shfl_xor(ss, o); }
    if (!ln) { sh[0][wv] = s; sh[1][wv] = ss; }
  }
  __syncthreads();
  if (!tid) {
    float S = 0.f, SS2 = 0.f;
    for (int i = 0; i < 8; ++i) { S += sh[0][i]; SS2 += sh[1][i]; }
    float n = (float)(BB * 600);
    float mean = S / n, var = SS2 / n - mean * mean;
    float a = (1.f / sqrtf(var + 1e-5f)) * g1[0];
    s_a1 = a; s_b1 = b1[0] - a * mean;
    if (blockIdx.x == 0) { ws[WS_STATS + 0] = a; ws[WS_STATS + 1] = s_b1; }
  }
  __syncthreads();
  int g = tid >> 8, t = tid & 255;
  int kbeg = g * 300, kend = kbeg + 300;
  for (int n = t; n < 300; n += 256) {
    float a0 = 0.f, a1v = 0.f;
    for (int k = kbeg; k < kend; ++k) {
      float wq = Wp1[k * 300 + n];
      a0 += ab[0][k] * wq;
      a1v += ab[1][k] * wq;
    }
    part[g][0][n] = a0;
    part[g][1][n] = a1v;
  }
  __syncthreads();
  float a1 = s_a1, beta1 = s_b1;
  float s2 = 0.f, ss2 = 0.f;
  for (int n = tid; n < 300; n += 512) {
    float c = beta1 * ws[WS_COLSUM + n] + ws[WS_CVEC + n];
    float v0 = a1 * (part[0][0][n] + part[1][0][n]) + c;
    float v1 = a1 * (part[0][1][n] + part[1][1][n]) + c;
    v0 = v0 > 0.f ? v0 : 0.f;
    v1 = v1 > 0.f ? v1 : 0.f;
    ws[WS_Y1 + b0 * 300 + n] = v0;
    ws[WS_Y1 + (b0 + 1) * 300 + n] = v1;
    s2 += v0 + v1; ss2 += v0 * v0 + v1 * v1;
  }
  for (int o = 32; o; o >>= 1) { s2 += __shfl_xor(s2, o); ss2 += __shfl_xor(ss2, o); }
  if (!ln) { sh[0][wv] = s2; sh[1][wv] = ss2; }
  __syncthreads();
  if (!tid) {
    float S = 0.f, SS2 = 0.f;
    for (int i = 0; i < 8; ++i) { S += sh[0][i]; SS2 += sh[1][i]; }
    ws[WS_PART2 + blockIdx.x * 2] = S;
    ws[WS_PART2 + blockIdx.x * 2 + 1] = SS2;
  }
}

// ---------------- k7: bn2 finalize + consts + out (wave per batch) ----------------
__launch_bounds__(256)
__global__ void k7(const float* __restrict__ g2, const float* __restrict__ b2,
                   float* __restrict__ out, const float* __restrict__ ws) {
  __shared__ float Gs[2400];
  __shared__ float sh[2][4];
  __shared__ float cc[4];   // a2, b2s, c0, c1
  int tid = threadIdx.x, wv = tid >> 6, ln = tid & 63;
  for (int i = tid; i < 2400; i += 256) Gs[i] = ws[WS_G + i];
  {
    float s = ws[WS_PART2 + tid * 2], ss = ws[WS_PART2 + tid * 2 + 1];
    for (int o = 32; o; o >>= 1) { s += __shfl_xor(s, o); ss += __shfl_xor(ss, o); }
    if (!ln) { sh[0][wv] = s; sh[1][wv] = ss; }
  }
  __syncthreads();
  if (!tid) {
    float S = 0.f, SS2 = 0.f;
    for (int i = 0; i < 4; ++i) { S += sh[0][i]; SS2 += sh[1][i]; }
    float n = (float)(BB * 300);
    float mean = S / n, var = SS2 / n - mean * mean;
    float a = (1.f / sqrtf(var + 1e-5f)) * g2[0];
    cc[0] = a; cc[1] = b2[0] - a * mean;
  }
  __syncthreads();
  if (tid < 2) {
    int c = tid;
    float sg1 = 0.f, sg2 = 0.f, sg3 = 0.f;
    for (int k = 0; k < 300; ++k) sg1 += Gs[k * 2 + c];
    for (int k = 300; k < 900; ++k) sg2 += Gs[k * 2 + c];
    for (int j = 0; j < 300; ++j) sg3 += ws[WS_CLS + j] * Gs[(900 + j) * 2 + c];
    cc[2 + c] = ws[WS_CST0 + c] + sg3 + cc[1] * sg1 + ws[WS_STATS + 1] * sg2;
  }
  __syncthreads();
  int b = blockIdx.x * 4 + wv;
  float a1 = ws[WS_STATS + 0], a2 = cc[0];
  const float* y1 = ws + WS_Y1 + b * 300;
  const float* ms = ws + WS_MSA + b * 600;
  float o0 = 0.f, o1 = 0.f, p0 = 0.f, p1 = 0.f;
  for (int k = ln; k < 300; k += 64) { float v = y1[k]; o0 += v * Gs[k * 2]; o1 += v * Gs[k * 2 + 1]; }
  for (int j = ln; j < 600; j += 64) { float v = ms[j]; p0 += v * Gs[(300 + j) * 2]; p1 += v * Gs[(300 + j) * 2 + 1]; }
  for (int o = 32; o; o >>= 1) {
    o0 += __shfl_xor(o0, o); o1 += __shfl_xor(o1, o);
    p0 += __shfl_xor(p0, o); p1 += __shfl_xor(p1, o);
  }
  if (!ln) {
    out[b * 2] = a2 * o0 + a1 * p0 + cc[2];
    out[b * 2 + 1] = a2 * o1 + a1 * p1 + cc[3];
  }
}

extern "C" void kernel_launch(void* const* d_in, const int* in_sizes, int n_in,
                              void* d_out, int out_size, void* d_ws, size_t ws_size,
                              hipStream_t stream) {
  const float* x    = (const float*)d_in[0];
  const float* Wp   = (const float*)d_in[1];
  const float* bp   = (const float*)d_in[2];
  const float* pos  = (const float*)d_in[3];
  const float* cle  = (const float*)d_in[4];
  const float* Wq   = (const float*)d_in[5];
  const float* Wk   = (const float*)d_in[6];
  const float* Wv   = (const float*)d_in[7];
  const float* bn1g = (const float*)d_in[8];
  const float* bn1b = (const float*)d_in[9];
  const float* Wp1  = (const float*)d_in[10];
  const float* bp1  = (const float*)d_in[11];
  const float* bn2g = (const float*)d_in[12];
  const float* bn2b = (const float*)d_in[13];
  const float* f1W  = (const float*)d_in[14];
  const float* f1b  = (const float*)d_in[15];
  const float* f2W  = (const float*)d_in[16];
  const float* f2b  = (const float*)d_in[17];
  float* ws = (float*)d_ws;
  float* out = (float*)d_out;

  hipLaunchKernelGGL(kC1, dim3(237), dim3(256), 0, stream, pos, cle, Wq, Wp1, Wp, Wv, f1W, f2W, f1b, f2b, ws);
  hipLaunchKernelGGL(kC2p, dim3(151), dim3(256), 0, stream, Wk, bp1, ws);
  hipLaunchKernelGGL(kA, dim3(512), dim3(512), 0, stream, x, bp, pos, ws);
  hipLaunchKernelGGL(kV, dim3(16), dim3(512), 0, stream, ws);
  hipLaunchKernelGGL(k5, dim3(256), dim3(512), 0, stream, Wp1, bn1g, bn1b, ws);
  hipLaunchKernelGGL(k7, dim3(128), dim3(256), 0, stream, bn2g, bn2b, out, ws);
}

// Round 16
// 117.949 us; speedup vs baseline: 1.5937x; 1.1309x over previous
//
#include <hip/hip_runtime.h>
#include <hip/hip_fp16.h>
#include <math.h>

#define BB 512
#define SS 100
#define DE 150
#define DM 300   // 2*D_E (also == D_IN)
#define LL 101
#define NH 2

typedef _Float16 f16x8 __attribute__((ext_vector_type(8)));
typedef float f32x4 __attribute__((ext_vector_type(4)));

// ---- ws layout (float offsets) ----
#define WS_CLS    0        // [300]
#define WS_QK     320      // [2][300]
#define WS_S0     960      // [2]
#define WS_CPOS   964      // [100][2]
#define WS_CVEC   1200     // [300]
#define WS_COLSUM 1536     // [300]
#define WS_CST0   1856     // [2]
#define WS_STATS  1860     // [0]=a1 [1]=beta1
#define WS_G      2176     // [1200][2]
#define WS_P3     5248     // [15][2][300]
#define WS_PART1  14336    // [16][2]   (kV blocks)
#define WS_PART2  15360    // [256][2]  (k5 blocks)
#define WS_MSA    16384                     // [512][600] f32
#define WS_Y1     (WS_MSA + 512*600)        // [512][300]  ends 477184
#define WS_WPF    477184   // fp16 [40][160][8] = 102,400 B (25,600 f32)
#define WS_WVF    502784   // fp16 [2][40][320][8] = 409,600 B (102,400 f32)
#define WS_ZB16   605184   // fp16 [2][512][320] = 655,360 B (163,840 f32)
#define WS_Q0P    769024   // [10][2][300] q0 partials

// ---------------- kC1: q0p | Wp1 partials | cls | G | CST0 | Wpf | Wvf ----------------
__global__ void kC1(const float* __restrict__ pos, const float* __restrict__ cle,
                    const float* __restrict__ Wq, const float* __restrict__ Wp1,
                    const float* __restrict__ Wp, const float* __restrict__ Wv,
                    const float* __restrict__ f1W, const float* __restrict__ f2W,
                    const float* __restrict__ f1b, const float* __restrict__ f2b,
                    float* __restrict__ ws) {
  __shared__ float cls[DM];
  int b = blockIdx.x, tid = threadIdx.x;
  if (b < 35) {
    for (int i = tid; i < DM; i += 256) cls[i] = (i < DE) ? cle[i] : pos[i - DE];
    __syncthreads();
  }
  if (b < 20) {
    int p = b >> 1, h = b & 1;
    const float* wqh = Wq + h * DM * DM;
    int d0 = p * 30;
    for (int e = tid; e < DM; e += 256) {
      float acc = 0.f;
#pragma unroll
      for (int d = 0; d < 30; ++d) acc += cls[d0 + d] * wqh[(d0 + d) * DM + e];
      ws[WS_Q0P + p * 600 + h * 300 + e] = acc;
    }
  } else if (b < 35) {
    int kb = b - 20;
    for (int n = tid; n < DM; n += 256) {
      float cs = 0.f, cv = 0.f;
      for (int k = kb * 60; k < kb * 60 + 60; ++k) {
        float w = Wp1[k * 300 + n];
        if (k < 600) cs += w; else cv += cls[k - 600] * w;
      }
      ws[WS_P3 + kb * 600 + n] = cs;
      ws[WS_P3 + kb * 600 + 300 + n] = cv;
    }
  } else if (b == 35) {
    for (int i = tid; i < DM; i += 256)
      ws[WS_CLS + i] = (i < DE) ? cle[i] : pos[i - DE];
  } else if (b < 111) {
    int wave = tid >> 6, lane = tid & 63;
    int kbase = (b - 36) * 16 + wave * 4;
#pragma unroll
    for (int j = 0; j < 4; ++j) {
      int k = kbase + j;
      const float* r = f1W + k * 512;
      float a0 = 0.f, a1 = 0.f;
      for (int m = lane; m < 512; m += 64) {
        float a = r[m];
        float2 f2 = *(const float2*)&f2W[m * 2];
        a0 += a * f2.x; a1 += a * f2.y;
      }
      for (int o = 32; o; o >>= 1) { a0 += __shfl_xor(a0, o); a1 += __shfl_xor(a1, o); }
      if (!lane) { ws[WS_G + k * 2] = a0; ws[WS_G + k * 2 + 1] = a1; }
    }
  } else if (b == 111) {
    int wave = tid >> 6, lane = tid & 63;
    if (wave < 2) {
      float acc = 0.f;
      for (int m = lane; m < 512; m += 64) acc += f1b[m] * f2W[m * 2 + wave];
      for (int o = 32; o; o >>= 1) acc += __shfl_xor(acc, o);
      if (!lane) ws[WS_CST0 + wave] = f2b[wave] + acc;
    }
  } else if (b < 137) {
    int idx = (b - 112) * 256 + tid;       // < 6400
    int kq = idx / 160, n = idx % 160;
    f16x8 pk;
#pragma unroll
    for (int j = 0; j < 8; ++j) {
      int k = kq * 8 + j;
      float v = (k < DM && n < DE) ? Wp[k * DE + n] : 0.f;
      pk[j] = (_Float16)v;
    }
    *(f16x8*)((char*)ws + (size_t)WS_WPF * 4 + (size_t)idx * 16) = pk;
  } else {
    int idx = (b - 137) * 256 + tid;       // < 25600
    int h = idx / 12800, rem = idx % 12800;
    int kq = rem / 320, n = rem % 320;
    f16x8 pk;
#pragma unroll
    for (int j = 0; j < 8; ++j) {
      int k = kq * 8 + j;
      float v = (k < DM && n < DM) ? Wv[h * DM * DM + k * DM + n] : 0.f;
      pk[j] = (_Float16)v;
    }
    *(f16x8*)((char*)ws + (size_t)WS_WVF * 4 + (size_t)idx * 16) = pk;
  }
}

// ---------------- kC2p: qk (blocks 0-149) | combine colsum/cvec (block 150) ----------------
__global__ void kC2p(const float* __restrict__ Wk, const float* __restrict__ bp1,
                     float* __restrict__ ws) {
  int b = blockIdx.x, tid = threadIdx.x;
  if (b == 150) {
    for (int n = tid; n < DM; n += 256) {
      float cs = 0.f, cv = bp1[n];
      for (int p = 0; p < 15; ++p) {
        cs += ws[WS_P3 + p * 600 + n];
        cv += ws[WS_P3 + p * 600 + 300 + n];
      }
      ws[WS_COLSUM + n] = cs;
      ws[WS_CVEC + n] = cv;
    }
    return;
  }
  __shared__ float q0s[NH * DM];
  for (int i = tid; i < NH * DM; i += 256) {
    float s = 0.f;
#pragma unroll
    for (int p = 0; p < 10; ++p) s += ws[WS_Q0P + p * 600 + i];
    q0s[i] = s;
  }
  __syncthreads();
  int wave = tid >> 6, lane = tid & 63;
  int idx = b * 4 + wave;            // < 600
  int h = idx / DM, d = idx % DM;
  const float* w = Wk + h * DM * DM + d * DM;
  const float* q = q0s + h * DM;
  float acc = 0.f;
  for (int e = lane; e < DM; e += 64) acc += w[e] * q[e];
  for (int o = 32; o; o >>= 1) acc += __shfl_xor(acc, o);
  if (!lane) ws[WS_QK + idx] = acc;
}

// ---------------- kC3: cpos (blocks 0-49) | s0 (block 50) ----------------
__global__ void kC3(const float* __restrict__ pos, float* __restrict__ ws) {
  int b = blockIdx.x, tid = threadIdx.x;
  int wave = tid >> 6, lane = tid & 63;
  if (b < 50) {
    int idx = b * 4 + wave;                   // < 200, = tt*2+h
    int tt = idx >> 1, h = idx & 1;
    const float* pr = pos + (tt + 1) * DE;
    const float* qk = ws + WS_QK + h * DM + DE;
    float acc = 0.f;
    for (int j = lane; j < DE; j += 64) acc += pr[j] * qk[j];
    for (int o = 32; o; o >>= 1) acc += __shfl_xor(acc, o);
    if (!lane) ws[WS_CPOS + idx] = acc;
  } else {
    if (wave < NH) {
      float acc = 0.f;
      for (int d = lane; d < DM; d += 64) acc += ws[WS_CLS + d] * ws[WS_QK + wave * DM + d];
      for (int o = 32; o; o >>= 1) acc += __shfl_xor(acc, o);
      if (!lane) ws[WS_S0 + wave] = acc;
    }
  }
}

// ---------------- kA: MFMA h-GEMM (dbuf LDS) -> scores -> softmax -> zbar16 (global) ----
__launch_bounds__(512, 4)
__global__ void kA(const float* __restrict__ x, const float* __restrict__ bp,
                   const float* __restrict__ pos, float* __restrict__ ws) {
  __shared__ __align__(16) char smem[41600];
  __half (*hb)[DE + 2] = (__half(*)[DE + 2])smem;
  _Float16* wpt0 = (_Float16*)(smem);
  _Float16* xs0  = (_Float16*)(smem + 10240);
  _Float16* wpt1 = (_Float16*)(smem + 18240);
  _Float16* xs1  = (_Float16*)(smem + 28480);
  float* aux = (float*)(smem + 36480);

  int b = blockIdx.x, tid = threadIdx.x;
  int w = tid >> 6, lane = tid & 63;
  int l16 = lane & 15, lg = lane >> 4;
  int wm = w >> 2, wn = w & 3;
  int nnt = (wn < 3) ? 3 : 1;
  int nt0 = (wn < 3) ? wn * 3 : 9;

  const float* xb = x + b * (SS * DM);
  const char* wpf = (const char*)ws + (size_t)WS_WPF * 4;
  int rowl[4];
#pragma unroll
  for (int mt = 0; mt < 4; ++mt) {
    int r = wm * 64 + mt * 16 + l16;
    rowl[mt] = (r < SS) ? r : (SS - 1);
  }

  f32x4 acc[4][3];
#pragma unroll
  for (int mt = 0; mt < 4; ++mt)
#pragma unroll
    for (int nti = 0; nti < 3; ++nti) acc[mt][nti] = (f32x4){0.f, 0.f, 0.f, 0.f};

  float xr[4][2];
  float4 wa, wb2;

#define XLOAD(S)                                                               \
  { int kc_ = (S) * 32;                                                        \
    _Pragma("unroll")                                                          \
    for (int i_ = 0; i_ < 4; ++i_) {                                           \
      int t_ = tid + 512 * i_;                                                 \
      if (t_ < 1600) {                                                         \
        int r_ = t_ >> 4, c_ = t_ & 15, k_ = kc_ + 2 * c_;                     \
        if (k_ + 1 < DM) {                                                     \
          float2 v_ = *(const float2*)(xb + r_ * DM + k_);                     \
          xr[i_][0] = v_.x; xr[i_][1] = v_.y;                                  \
        } else {                                                               \
          xr[i_][0] = (k_ < DM) ? xb[r_ * DM + k_] : 0.f;                      \
          xr[i_][1] = 0.f;                                                     \
        } } } }

#define XWRITE(XP)                                                             \
  { _Pragma("unroll")                                                          \
    for (int i_ = 0; i_ < 4; ++i_) {                                           \
      int t_ = tid + 512 * i_;                                                 \
      if (t_ < 1600) {                                                         \
        int r_ = t_ >> 4, c_ = t_ & 15;                                        \
        *(__half2*)((char*)(XP) + r_ * 80 + c_ * 4) =                          \
            __floats2half2_rn(xr[i_][0], xr[i_][1]);                           \
      } } }

#define WLOAD(S)                                                               \
  { const char* s_ = wpf + (size_t)(S) * 10240;                                \
    wa = *(const float4*)(s_ + tid * 16);                                      \
    if (tid < 128) wb2 = *(const float4*)(s_ + (tid + 512) * 16); }

#define WWRITE(WP)                                                             \
  { *(float4*)((char*)(WP) + tid * 16) = wa;                                   \
    if (tid < 128) *(float4*)((char*)(WP) + (tid + 512) * 16) = wb2; }

  XLOAD(0); WLOAD(0);
  XWRITE(xs0); WWRITE(wpt0);
  __syncthreads();

  for (int s = 0; s < 10; ++s) {
    _Float16* wc = (s & 1) ? wpt1 : wpt0;
    _Float16* xc = (s & 1) ? xs1 : xs0;
    _Float16* wnx = (s & 1) ? wpt0 : wpt1;
    _Float16* xnx = (s & 1) ? xs0 : xs1;
    if (s < 9) { WLOAD(s + 1); XLOAD(s + 1); }
    f16x8 Bf[3];
#pragma unroll
    for (int nti = 0; nti < 3; ++nti)
      if (nti < nnt)
        Bf[nti] = *(const f16x8*)(wc + ((lg * 160 + (nt0 + nti) * 16 + l16) * 8));
#pragma unroll
    for (int mt = 0; mt < 4; ++mt) {
      f16x8 Af = *(const f16x8*)(xc + rowl[mt] * 40 + lg * 8);
#pragma unroll
      for (int nti = 0; nti < 3; ++nti)
        if (nti < nnt)
          acc[mt][nti] = __builtin_amdgcn_mfma_f32_16x16x32_f16(Af, Bf[nti], acc[mt][nti], 0, 0, 0);
    }
    if (s < 9) { WWRITE(wnx); XWRITE(xnx); }
    __syncthreads();
  }

  // hb = relu(acc + bp) fp16 (aliases dead GEMM buffers)
#pragma unroll
  for (int nti = 0; nti < 3; ++nti) {
    if (nti < nnt) {
      int col = (nt0 + nti) * 16 + l16;
      float bpv = (col < DE) ? bp[col] : 0.f;
#pragma unroll
      for (int mt = 0; mt < 4; ++mt) {
        int rbase = wm * 64 + mt * 16 + lg * 4;
        f32x4 v = acc[mt][nti];
#pragma unroll
        for (int reg = 0; reg < 4; ++reg) {
          int row = rbase + reg;
          if (row < SS && col < DE) {
            float hv = v[reg] + bpv;
            hb[row][col] = __float2half(hv > 0.f ? hv : 0.f);
          }
        }
      }
    }
  }
  for (int i = tid; i < DM; i += 512) {
    aux[i] = ws[WS_QK + (i / DE) * DM + (i % DE)];
    aux[DM + i] = ws[WS_CLS + i];
  }
  __syncthreads();

  // phase 2: scores (hb as half2) + precomputed cpos/s0
  if (tid < NH * SS) {
    int hh = tid / SS, tt = tid % SS;
    const __half2* hr = (const __half2*)&hb[tt][0];
    const float* qr = &aux[hh * DE];
    float s = 0.f;
    for (int j2 = 0; j2 < DE / 2; ++j2) {
      float2 hv = __half22float2(hr[j2]);
      float2 qv = *(const float2*)&qr[2 * j2];
      s += hv.x * qv.x + hv.y * qv.y;
    }
    aux[600 + hh * LL + tt + 1] = s + ws[WS_CPOS + tt * NH + hh];
  } else if (tid < NH * SS + NH) {
    int hh = tid - NH * SS;
    aux[600 + hh * LL] = ws[WS_S0 + hh];
  }
  __syncthreads();

  // phase 3: softmax (one wave per head)
  if (w < NH) {
    float v0 = aux[600 + w * LL + lane];
    float v1 = (lane + 64 < LL) ? aux[600 + w * LL + lane + 64] : -1e30f;
    float m = fmaxf(v0, v1);
    for (int o = 32; o; o >>= 1) m = fmaxf(m, __shfl_xor(m, o));
    float e0 = expf(v0 - m);
    float e1 = (lane + 64 < LL) ? expf(v1 - m) : 0.f;
    float s = e0 + e1;
    for (int o = 32; o; o >>= 1) s += __shfl_xor(s, o);
    float inv = 1.f / s;
    aux[802 + w * LL + lane] = e0 * inv;
    if (lane + 64 < LL) aux[802 + w * LL + lane + 64] = e1 * inv;
  }
  __syncthreads();

  // phase 4: zbar -> global fp16 [h][512][320]
  __half* zb16 = (__half*)((char*)ws + (size_t)WS_ZB16 * 4);
  for (int o = tid; o < NH * DM; o += 512) {
    int hh = o / DM, d = o % DM;
    const float* p = &aux[802 + hh * LL];
    float acc2 = p[0] * aux[DM + d];
    if (d < DE) {
      for (int t = 1; t <= SS; ++t) acc2 += p[t] * __half2float(hb[t - 1][d]);
    } else {
      int dd = d - DE;
      for (int t = 1; t <= SS; ++t) acc2 += p[t] * pos[t * DE + dd];
    }
    zb16[((size_t)hh * 512 + b) * 320 + d] = __float2half(acc2);
  }
  if (tid < 40) {
    int hh = tid / 20, dd = 300 + tid % 20;
    zb16[((size_t)hh * 512 + b) * 320 + dd] = __float2half(0.f);
  }
}

// ---------------- kV: msa = zbar16 @ Wvf (MFMA, L2-direct) + bn1 partials ----------------
__launch_bounds__(512, 4)
__global__ void kV(float* __restrict__ ws) {
  __shared__ float shp[2][8];
  int blk = blockIdx.x;
  int mtile = blk >> 2, nb = (blk >> 1) & 1, h = blk & 1;
  int tid = threadIdx.x;
  int w = tid >> 6, lane = tid & 63;
  int l16 = lane & 15, lg = lane >> 4;
  int wm = w >> 2, wn = w & 3;
  int nnt = (wn < 3) ? 3 : 1;
  int nt0 = (wn < 3) ? wn * 3 : 9;
  int mbase = mtile * 128;

  const __half* zb16 = (const __half*)((const char*)ws + (size_t)WS_ZB16 * 4) + (size_t)h * 512 * 320;
  const __half* wvf  = (const __half*)((const char*)ws + (size_t)WS_WVF * 4) + (size_t)h * 40 * 320 * 8;

  int brow[4];
#pragma unroll
  for (int mt = 0; mt < 4; ++mt) brow[mt] = mbase + wm * 64 + mt * 16 + l16;

  f32x4 acc[4][3];
#pragma unroll
  for (int mt = 0; mt < 4; ++mt)
#pragma unroll
    for (int nti = 0; nti < 3; ++nti) acc[mt][nti] = (f32x4){0.f, 0.f, 0.f, 0.f};

  for (int s = 0; s < 10; ++s) {
    f16x8 Bf[3];
#pragma unroll
    for (int nti = 0; nti < 3; ++nti)
      if (nti < nnt) {
        int n = nb * 160 + (nt0 + nti) * 16 + l16;
        Bf[nti] = *(const f16x8*)&wvf[((size_t)(s * 4 + lg) * 320 + n) * 8];
      }
#pragma unroll
    for (int mt = 0; mt < 4; ++mt) {
      f16x8 Af = *(const f16x8*)&zb16[(size_t)brow[mt] * 320 + s * 32 + lg * 8];
#pragma unroll
      for (int nti = 0; nti < 3; ++nti)
        if (nti < nnt)
          acc[mt][nti] = __builtin_amdgcn_mfma_f32_16x16x32_f16(Af, Bf[nti], acc[mt][nti], 0, 0, 0);
    }
  }

  float s_ = 0.f, ss_ = 0.f;
#pragma unroll
  for (int nti = 0; nti < 3; ++nti) {
    if (nti < nnt) {
      int col = nb * 160 + (nt0 + nti) * 16 + l16;
      if (col < DM) {
#pragma unroll
        for (int mt = 0; mt < 4; ++mt) {
          int rbase = mbase + wm * 64 + mt * 16 + lg * 4;
          f32x4 v = acc[mt][nti];
#pragma unroll
          for (int reg = 0; reg < 4; ++reg) {
            int row = rbase + reg;
            float val = v[reg];
            ws[WS_MSA + row * 600 + h * DM + col] = val;
            s_ += val; ss_ += val * val;
          }
        }
      }
    }
  }
  for (int o = 32; o; o >>= 1) { s_ += __shfl_xor(s_, o); ss_ += __shfl_xor(ss_, o); }
  if (!lane) { shp[0][w] = s_; shp[1][w] = ss_; }
  __syncthreads();
  if (!tid) {
    float S = 0.f, SS2 = 0.f;
    for (int i = 0; i < 8; ++i) { S += shp[0][i]; SS2 += shp[1][i]; }
    ws[WS_PART1 + blk * 2] = S;
    ws[WS_PART1 + blk * 2 + 1] = SS2;
  }
}

// ---------------- k5: bn1 finalize + y1 (split-K x2) + bn2 per-block partial ----------------
__launch_bounds__(512)
__global__ void k5(const float* __restrict__ Wp1, const float* __restrict__ g1,
                   const float* __restrict__ b1, float* __restrict__ ws) {
  __shared__ float ab[2][600];
  __shared__ float part[2][2][300];
  __shared__ float sh[2][8];
  __shared__ float s_a1, s_b1;
  int b0 = blockIdx.x * 2, tid = threadIdx.x;
  int wv = tid >> 6, ln = tid & 63;
  for (int i = tid; i < 1200; i += 512) ab[i / 600][i % 600] = ws[WS_MSA + b0 * 600 + i];
  {
    float s = 0.f, ss = 0.f;
    if (tid < 16) { s = ws[WS_PART1 + tid * 2]; ss = ws[WS_PART1 + tid * 2 + 1]; }
    for (int o = 32; o; o >>= 1) { s += __shfl_xor(s, o); ss += __shfl_xor(ss, o); }
    if (!ln) { sh[0][wv] = s; sh[1][wv] = ss; }
  }
  __syncthreads();
  if (!tid) {
    float S = 0.f, SS2 = 0.f;
    for (int i = 0; i < 8; ++i) { S += sh[0][i]; SS2 += sh[1][i]; }
    float n = (float)(BB * 600);
    float mean = S / n, var = SS2 / n - mean * mean;
    float a = (1.f / sqrtf(var + 1e-5f)) * g1[0];
    s_a1 = a; s_b1 = b1[0] - a * mean;
    if (blockIdx.x == 0) { ws[WS_STATS + 0] = a; ws[WS_STATS + 1] = s_b1; }
  }
  __syncthreads();
  int g = tid >> 8, t = tid & 255;
  int kbeg = g * 300, kend = kbeg + 300;
  for (int n = t; n < 300; n += 256) {
    float a0 = 0.f, a1v = 0.f;
    for (int k = kbeg; k < kend; ++k) {
      float wq = Wp1[k * 300 + n];
      a0 += ab[0][k] * wq;
      a1v += ab[1][k] * wq;
    }
    part[g][0][n] = a0;
    part[g][1][n] = a1v;
  }
  __syncthreads();
  float a1 = s_a1, beta1 = s_b1;
  float s2 = 0.f, ss2 = 0.f;
  for (int n = tid; n < 300; n += 512) {
    float c = beta1 * ws[WS_COLSUM + n] + ws[WS_CVEC + n];
    float v0 = a1 * (part[0][0][n] + part[1][0][n]) + c;
    float v1 = a1 * (part[0][1][n] + part[1][1][n]) + c;
    v0 = v0 > 0.f ? v0 : 0.f;
    v1 = v1 > 0.f ? v1 : 0.f;
    ws[WS_Y1 + b0 * 300 + n] = v0;
    ws[WS_Y1 + (b0 + 1) * 300 + n] = v1;
    s2 += v0 + v1; ss2 += v0 * v0 + v1 * v1;
  }
  for (int o = 32; o; o >>= 1) { s2 += __shfl_xor(s2, o); ss2 += __shfl_xor(ss2, o); }
  if (!ln) { sh[0][wv] = s2; sh[1][wv] = ss2; }
  __syncthreads();
  if (!tid) {
    float S = 0.f, SS2 = 0.f;
    for (int i = 0; i < 8; ++i) { S += sh[0][i]; SS2 += sh[1][i]; }
    ws[WS_PART2 + blockIdx.x * 2] = S;
    ws[WS_PART2 + blockIdx.x * 2 + 1] = SS2;
  }
}

// ---------------- k7: bn2 finalize + consts + out (wave per batch) ----------------
__launch_bounds__(256)
__global__ void k7(const float* __restrict__ g2, const float* __restrict__ b2,
                   float* __restrict__ out, const float* __restrict__ ws) {
  __shared__ float Gs[2400];
  __shared__ float sh[2][4];
  __shared__ float cc[4];   // a2, b2s, c0, c1
  int tid = threadIdx.x, wv = tid >> 6, ln = tid & 63;
  for (int i = tid; i < 2400; i += 256) Gs[i] = ws[WS_G + i];
  {
    float s = ws[WS_PART2 + tid * 2], ss = ws[WS_PART2 + tid * 2 + 1];
    for (int o = 32; o; o >>= 1) { s += __shfl_xor(s, o); ss += __shfl_xor(ss, o); }
    if (!ln) { sh[0][wv] = s; sh[1][wv] = ss; }
  }
  __syncthreads();
  if (!tid) {
    float S = 0.f, SS2 = 0.f;
    for (int i = 0; i < 4; ++i) { S += sh[0][i]; SS2 += sh[1][i]; }
    float n = (float)(BB * 300);
    float mean = S / n, var = SS2 / n - mean * mean;
    float a = (1.f / sqrtf(var + 1e-5f)) * g2[0];
    cc[0] = a; cc[1] = b2[0] - a * mean;
  }
  __syncthreads();
  if (tid < 2) {
    int c = tid;
    float sg1 = 0.f, sg2 = 0.f, sg3 = 0.f;
    for (int k = 0; k < 300; ++k) sg1 += Gs[k * 2 + c];
    for (int k = 300; k < 900; ++k) sg2 += Gs[k * 2 + c];
    for (int j = 0; j < 300; ++j) sg3 += ws[WS_CLS + j] * Gs[(900 + j) * 2 + c];
    cc[2 + c] = ws[WS_CST0 + c] + sg3 + cc[1] * sg1 + ws[WS_STATS + 1] * sg2;
  }
  __syncthreads();
  int b = blockIdx.x * 4 + wv;
  float a1 = ws[WS_STATS + 0], a2 = cc[0];
  const float* y1 = ws + WS_Y1 + b * 300;
  const float* ms = ws + WS_MSA + b * 600;
  float o0 = 0.f, o1 = 0.f, p0 = 0.f, p1 = 0.f;
  for (int k = ln; k < 300; k += 64) { float v = y1[k]; o0 += v * Gs[k * 2]; o1 += v * Gs[k * 2 + 1]; }
  for (int j = ln; j < 600; j += 64) { float v = ms[j]; p0 += v * Gs[(300 + j) * 2]; p1 += v * Gs[(300 + j) * 2 + 1]; }
  for (int o = 32; o; o >>= 1) {
    o0 += __shfl_xor(o0, o); o1 += __shfl_xor(o1, o);
    p0 += __shfl_xor(p0, o); p1 += __shfl_xor(p1, o);
  }
  if (!ln) {
    out[b * 2] = a2 * o0 + a1 * p0 + cc[2];
    out[b * 2 + 1] = a2 * o1 + a1 * p1 + cc[3];
  }
}

extern "C" void kernel_launch(void* const* d_in, const int* in_sizes, int n_in,
                              void* d_out, int out_size, void* d_ws, size_t ws_size,
                              hipStream_t stream) {
  const float* x    = (const float*)d_in[0];
  const float* Wp   = (const float*)d_in[1];
  const float* bp   = (const float*)d_in[2];
  const float* pos  = (const float*)d_in[3];
  const float* cle  = (const float*)d_in[4];
  const float* Wq   = (const float*)d_in[5];
  const float* Wk   = (const float*)d_in[6];
  const float* Wv   = (const float*)d_in[7];
  const float* bn1g = (const float*)d_in[8];
  const float* bn1b = (const float*)d_in[9];
  const float* Wp1  = (const float*)d_in[10];
  const float* bp1  = (const float*)d_in[11];
  const float* bn2g = (const float*)d_in[12];
  const float* bn2b = (const float*)d_in[13];
  const float* f1W  = (const float*)d_in[14];
  const float* f1b  = (const float*)d_in[15];
  const float* f2W  = (const float*)d_in[16];
  const float* f2b  = (const float*)d_in[17];
  float* ws = (float*)d_ws;
  float* out = (float*)d_out;

  hipLaunchKernelGGL(kC1, dim3(237), dim3(256), 0, stream, pos, cle, Wq, Wp1, Wp, Wv, f1W, f2W, f1b, f2b, ws);
  hipLaunchKernelGGL(kC2p, dim3(151), dim3(256), 0, stream, Wk, bp1, ws);
  hipLaunchKernelGGL(kC3, dim3(51), dim3(256), 0, stream, pos, ws);
  hipLaunchKernelGGL(kA, dim3(512), dim3(512), 0, stream, x, bp, pos, ws);
  hipLaunchKernelGGL(kV, dim3(16), dim3(512), 0, stream, ws);
  hipLaunchKernelGGL(k5, dim3(256), dim3(512), 0, stream, Wp1, bn1g, bn1b, ws);
  hipLaunchKernelGGL(k7, dim3(128), dim3(256), 0, stream, bn2g, bn2b, out, ws);
}